// Round 9
// baseline (30.698 us; speedup 1.0000x reference)
//
#include <hip/hip_runtime.h>
#include <float.h>

// Chamfer distance, B=16, N=2048, D=3, fp32.
// cd[b] = mean_j min_i |x_i - y_j|^2 + mean_i min_j |x_i - y_j|^2
// Pair form: |q - r|^2 = 2*(0.5|r|^2 - q.r) + |q|^2.
// Structure: [min -> partial] then [fused combine+final -> out], 2 dispatches.
// Min inner loop: scalar v_fma_f32 (full-rate; v_pk_fma_f32 is half-rate on
// gfx950: 157.3 TF == scalar rate) + v_min3_f32 = 3.5 instr/pair. Refs in
// LDS SoA rows, 4 refs per broadcast ds_read_b128, QPT=8 amortization.

constexpr int B_ = 16;
constexpr int N_ = 2048;
constexpr int THREADS = 256;
constexpr int QPT = 8;                  // queries per thread; THREADS*QPT == N_
constexpr int NJC = 32;                 // ref chunks
constexpr int CHUNK = N_ / NJC;         // 64 refs per chunk

typedef float v4f __attribute__((ext_vector_type(4)));

// ws layout: float partial[2][B_][NJC][N_] (8 MiB)

__global__ __launch_bounds__(THREADS)
void cd_min_kernel(const float* __restrict__ x,
                   const float* __restrict__ y,
                   float* __restrict__ partial) {
    const int jc  = blockIdx.x;
    const int b   = blockIdx.y;
    const int dir = blockIdx.z;

    const float* __restrict__ q = dir ? y : x;
    const float* __restrict__ r = dir ? x : y;

    // ---- stage ref chunk into LDS, SoA + half-norm row ----
    __shared__ float lref[4][CHUNK];    // [x|y|z|0.5*|r|^2][point]
    {
        const float* __restrict__ rp =
            r + ((size_t)b * N_ + (size_t)jc * CHUNK) * 3;
        for (int p = (int)threadIdx.x; p < CHUNK; p += THREADS) {
            const float rx = rp[3 * p + 0];
            const float ry = rp[3 * p + 1];
            const float rz = rp[3 * p + 2];
            lref[0][p] = rx;
            lref[1][p] = ry;
            lref[2][p] = rz;
            lref[3][p] = 0.5f * (rx * rx + ry * ry + rz * rz);
        }
    }

    // ---- per-thread query registers ----
    const int i0 = (int)threadIdx.x * QPT;
    const float* qp = q + ((size_t)b * N_ + i0) * 3;

    float qf[24];
    {
        const float4* qv = (const float4*)qp;
        #pragma unroll
        for (int v = 0; v < 6; ++v) {
            const float4 t = qv[v];
            qf[4 * v + 0] = t.x; qf[4 * v + 1] = t.y;
            qf[4 * v + 2] = t.z; qf[4 * v + 3] = t.w;
        }
    }
    float qnx[QPT], qny[QPT], qnz[QPT], q2[QPT], best[QPT];
    #pragma unroll
    for (int k = 0; k < QPT; ++k) {
        const float a0 = qf[3 * k + 0];
        const float a1 = qf[3 * k + 1];
        const float a2 = qf[3 * k + 2];
        qnx[k] = -a0; qny[k] = -a1; qnz[k] = -a2;
        q2[k]  = a0 * a0 + a1 * a1 + a2 * a2;
        best[k] = FLT_MAX;
    }
    __syncthreads();

    // ---- main loop: 4 refs/group via 4x broadcast ds_read_b128 ----
    const v4f* __restrict__ lx = (const v4f*)lref[0];
    const v4f* __restrict__ ly = (const v4f*)lref[1];
    const v4f* __restrict__ lz = (const v4f*)lref[2];
    const v4f* __restrict__ lh = (const v4f*)lref[3];

    #pragma unroll 2
    for (int g = 0; g < CHUNK / 4; ++g) {
        const v4f X = lx[g], Y = ly[g], Z = lz[g], H = lh[g];
        #pragma unroll
        for (int k = 0; k < QPT; ++k) {
            float a0 = fmaf(qnx[k], X.x, H.x);
            a0 = fmaf(qny[k], Y.x, a0);
            a0 = fmaf(qnz[k], Z.x, a0);
            float a1 = fmaf(qnx[k], X.y, H.y);
            a1 = fmaf(qny[k], Y.y, a1);
            a1 = fmaf(qnz[k], Z.y, a1);
            float a2 = fmaf(qnx[k], X.z, H.z);
            a2 = fmaf(qny[k], Y.z, a2);
            a2 = fmaf(qnz[k], Z.z, a2);
            float a3 = fmaf(qnx[k], X.w, H.w);
            a3 = fmaf(qny[k], Y.w, a3);
            a3 = fmaf(qnz[k], Z.w, a3);
            best[k] = fminf(fminf(best[k], a0), a1);
            best[k] = fminf(fminf(best[k], a2), a3);
        }
    }

    float res[QPT];
    #pragma unroll
    for (int k = 0; k < QPT; ++k)
        res[k] = 2.0f * best[k] + q2[k];

    float4* op = (float4*)(partial
        + (((size_t)dir * B_ + b) * NJC + jc) * N_ + i0);
    op[0] = *(float4*)&res[0];
    op[1] = *(float4*)&res[4];
}

// Fused combine+final: one block per batch b. For each of 2 dirs and each
// query position: min over NJC chunk-partials (float4 x 4 positions per
// thread per pass, coalesced 1 KiB/wave-instr), accumulate sum of mins for
// BOTH dirs, block-reduce, out[b] = sum / N.
__global__ __launch_bounds__(THREADS)
void cd_combine_final_kernel(const float* __restrict__ partial,
                             float* __restrict__ out) {
    const int b = blockIdx.x;
    const int t = (int)threadIdx.x;

    float sum = 0.0f;
    #pragma unroll
    for (int dir = 0; dir < 2; ++dir) {
        const float* __restrict__ base =
            partial + ((size_t)dir * B_ + b) * (size_t)NJC * N_;
        // 2048 positions per dir; 256 threads x 4 floats = 1024/pass, 2 passes.
        #pragma unroll
        for (int pass = 0; pass < 2; ++pass) {
            const int pos = (pass * THREADS + t) * 4;
            const float* p = base + pos;
            v4f m = (v4f){FLT_MAX, FLT_MAX, FLT_MAX, FLT_MAX};
            #pragma unroll
            for (int c = 0; c < NJC; ++c) {
                const v4f v = *(const v4f*)(p + (size_t)c * N_);
                m = __builtin_elementwise_min(m, v);
            }
            sum += (m.x + m.y) + (m.z + m.w);
        }
    }

    // block reduce: wave64 shuffle, then LDS across 4 waves.
    #pragma unroll
    for (int o = 32; o > 0; o >>= 1)
        sum += __shfl_down(sum, o, 64);

    __shared__ float red[THREADS / 64];
    if ((t & 63) == 0) red[t >> 6] = sum;
    __syncthreads();
    if (t == 0) {
        float tot = 0.0f;
        #pragma unroll
        for (int w = 0; w < THREADS / 64; ++w) tot += red[w];
        out[b] = tot * (1.0f / (float)N_);
    }
}

extern "C" void kernel_launch(void* const* d_in, const int* in_sizes, int n_in,
                              void* d_out, int out_size, void* d_ws, size_t ws_size,
                              hipStream_t stream) {
    const float* x = (const float*)d_in[0];
    const float* y = (const float*)d_in[1];
    float* out     = (float*)d_out;
    float* partial = (float*)d_ws;   // 8 MiB

    cd_min_kernel<<<dim3(NJC, B_, 2), dim3(THREADS), 0, stream>>>(x, y, partial);
    cd_combine_final_kernel<<<dim3(B_), dim3(THREADS), 0, stream>>>(partial, out);
}

// Round 10
// 24.337 us; speedup vs baseline: 1.2614x; 1.2614x over previous
//
#include <hip/hip_runtime.h>
#include <float.h>

// Chamfer distance, B=16, N=2048, D=3, fp32.
// cd[b] = mean_j min_i |x_i - y_j|^2 + mean_i min_j |x_i - y_j|^2
// Pair form: |q - r|^2 = 2*(0.5|r|^2 - q.r) + |q|^2.
// Structure (round 10): each block stages the ENTIRE ref set for (b,dir)
// in 32 KB LDS (SoA + halfnorm), computes FINAL per-query minima for its
// 64-query slice (thread = query x ref-quarter), block-reduces to ONE
// float. No 8 MiB partial round-trip, no combine kernel: 2 dispatches,
// 4 KiB intermediate. Inner loop: scalar v_fma_f32 (full-rate; packed is
// half-rate on gfx950) + v_min3_f32 = 3.5 instr/pair.

constexpr int B_ = 16;
constexpr int N_ = 2048;
constexpr int THREADS = 256;
constexpr int QS = 32;                    // query slices per (b,dir)
constexpr int QBLK = N_ / QS;             // 64 queries per block
constexpr int RSPLIT = THREADS / QBLK;    // 4 ref-quarters
constexpr int RCHUNK = N_ / RSPLIT;       // 512 refs per thread
constexpr int PPT = N_ / THREADS;         // 8 ref points staged per thread

typedef float v4f __attribute__((ext_vector_type(4)));

// ws layout: float sums[2][B_][QS]  (1024 floats)

__global__ __launch_bounds__(THREADS)
void cd_min_kernel(const float* __restrict__ x,
                   const float* __restrict__ y,
                   float* __restrict__ sums) {
    const int qs  = blockIdx.x;           // 0..31
    const int b   = blockIdx.y;           // 0..15
    const int dir = blockIdx.z;           // 0..1
    const int t   = (int)threadIdx.x;

    const float* __restrict__ q = dir ? y : x;
    const float* __restrict__ r = dir ? x : y;

    // ---- stage ALL refs for (b,dir) into LDS: SoA + halfnorm ----
    __shared__ __align__(16) float lref[4][N_];   // 32 KB
    {
        const int p0 = t * PPT;                   // 8 points = 96 B contiguous
        const float4* rv = (const float4*)(r + ((size_t)b * N_ + p0) * 3);
        float buf[3 * PPT];
        #pragma unroll
        for (int v = 0; v < 6; ++v) {
            const float4 tv = rv[v];
            buf[4 * v + 0] = tv.x; buf[4 * v + 1] = tv.y;
            buf[4 * v + 2] = tv.z; buf[4 * v + 3] = tv.w;
        }
        #pragma unroll
        for (int k = 0; k < PPT; ++k) {
            const float rx = buf[3 * k + 0];
            const float ry = buf[3 * k + 1];
            const float rz = buf[3 * k + 2];
            lref[0][p0 + k] = rx;
            lref[1][p0 + k] = ry;
            lref[2][p0 + k] = rz;
            lref[3][p0 + k] = 0.5f * (rx * rx + ry * ry + rz * rz);
        }
    }

    // ---- this thread's query (4 threads share one query, rq differs) ----
    const int qi = t & (QBLK - 1);        // query within slice
    const int rq = t >> 6;                // ref-quarter; wave-uniform (t>>6)
    const float* qp = q + ((size_t)b * N_ + (size_t)qs * QBLK + qi) * 3;
    const float qx = qp[0], qy = qp[1], qz = qp[2];
    const float qnx = -qx, qny = -qy, qnz = -qz;
    const float q2 = qx * qx + qy * qy + qz * qz;

    __syncthreads();

    // ---- min over this thread's 512 refs: broadcast ds_read_b128 ----
    const v4f* __restrict__ lx = (const v4f*)lref[0];
    const v4f* __restrict__ ly = (const v4f*)lref[1];
    const v4f* __restrict__ lz = (const v4f*)lref[2];
    const v4f* __restrict__ lh = (const v4f*)lref[3];

    const int g0 = rq * (RCHUNK / 4);
    float best = FLT_MAX;
    #pragma unroll 4
    for (int g = g0; g < g0 + RCHUNK / 4; ++g) {
        const v4f X = lx[g], Y = ly[g], Z = lz[g], H = lh[g];
        float a0 = fmaf(qnx, X.x, H.x);
        a0 = fmaf(qny, Y.x, a0);
        a0 = fmaf(qnz, Z.x, a0);
        float a1 = fmaf(qnx, X.y, H.y);
        a1 = fmaf(qny, Y.y, a1);
        a1 = fmaf(qnz, Z.y, a1);
        float a2 = fmaf(qnx, X.z, H.z);
        a2 = fmaf(qny, Y.z, a2);
        a2 = fmaf(qnz, Z.z, a2);
        float a3 = fmaf(qnx, X.w, H.w);
        a3 = fmaf(qny, Y.w, a3);
        a3 = fmaf(qnz, Z.w, a3);
        best = fminf(fminf(best, a0), a1);    // v_min3_f32
        best = fminf(fminf(best, a2), a3);    // v_min3_f32
    }

    // ---- combine ref-quarters, then block-sum the 64 query minima ----
    __shared__ float cmin[RSPLIT][QBLK];      // 1 KB
    cmin[rq][qi] = best;
    __syncthreads();

    if (t < QBLK) {                           // wave 0 only (t<64, rq==0)
        float m = fminf(fminf(cmin[0][t], cmin[1][t]),
                        fminf(cmin[2][t], cmin[3][t]));
        float val = 2.0f * m + q2;            // qi==t for these threads
        #pragma unroll
        for (int o = 32; o > 0; o >>= 1)
            val += __shfl_down(val, o, 64);
        if (t == 0)
            sums[((size_t)dir * B_ + b) * QS + qs] = val;
    }
}

// Final: 1 block. t -> b = t>>4, k = t&15; each k sums 4 of the 64
// (dir,slice) entries for its batch, then width-16 shuffle reduce.
__global__ __launch_bounds__(THREADS)
void cd_final_kernel(const float* __restrict__ sums,
                     float* __restrict__ out) {
    const int t = (int)threadIdx.x;
    const int b = t >> 4;
    const int k = t & 15;

    float v = 0.0f;
    #pragma unroll
    for (int j = 0; j < 4; ++j) {
        const int f   = k * 4 + j;            // 0..63
        const int dir = f >> 5;
        const int qs  = f & 31;
        v += sums[((size_t)dir * B_ + b) * QS + qs];
    }
    v += __shfl_down(v, 8, 16);
    v += __shfl_down(v, 4, 16);
    v += __shfl_down(v, 2, 16);
    v += __shfl_down(v, 1, 16);
    if (k == 0) out[b] = v * (1.0f / (float)N_);
}

extern "C" void kernel_launch(void* const* d_in, const int* in_sizes, int n_in,
                              void* d_out, int out_size, void* d_ws, size_t ws_size,
                              hipStream_t stream) {
    const float* x = (const float*)d_in[0];
    const float* y = (const float*)d_in[1];
    float* out     = (float*)d_out;
    float* sums    = (float*)d_ws;            // 4 KiB

    cd_min_kernel<<<dim3(QS, B_, 2), dim3(THREADS), 0, stream>>>(x, y, sums);
    cd_final_kernel<<<dim3(1), dim3(THREADS), 0, stream>>>(sums, out);
}